// Round 2
// baseline (29582.233 us; speedup 1.0000x reference)
//
#include <hip/hip_runtime.h>

// Problem constants
#define Bc   64
#define Tc   512
#define NINc 256
#define Hc   512
#define NOUTc 256
#define NBLK 256
#define NTHR 256

__device__ __forceinline__ double dsig(double x) { return 1.0 / (1.0 + exp(-x)); }

// Monotonic-counter grid barrier. cnt is zeroed by host memset each launch.
__device__ __forceinline__ void gridbar(unsigned* cnt, unsigned target) {
  __syncthreads();
  if (threadIdx.x == 0) {
    __hip_atomic_fetch_add(cnt, 1u, __ATOMIC_ACQ_REL, __HIP_MEMORY_SCOPE_AGENT);
    while (__hip_atomic_load(cnt, __ATOMIC_RELAXED, __HIP_MEMORY_SCOPE_AGENT) < target) {
      __builtin_amdgcn_s_sleep(2);
    }
    (void)__hip_atomic_load(cnt, __ATOMIC_ACQUIRE, __HIP_MEMORY_SCOPE_AGENT);
  }
  __syncthreads();
}

// 8-row dot-product chunk, A strided by Bc floats per k (activations in [K][B] layout)
// f64 accumulation to minimize divergence from the numpy reference.
__device__ __forceinline__ void dot8_sb(const float* __restrict__ A,
                                        const float* __restrict__ W,
                                        const int wstride, const int nk,
                                        double* __restrict__ acc) {
#pragma unroll 2
  for (int k = 0; k < nk; k += 4) {
    double a0 = (double)A[(k + 0) * Bc];
    double a1 = (double)A[(k + 1) * Bc];
    double a2 = (double)A[(k + 2) * Bc];
    double a3 = (double)A[(k + 3) * Bc];
#pragma unroll
    for (int r = 0; r < 8; ++r) {
      float4 w = *(const float4*)(W + r * wstride + k);
      acc[r] = fma(a0, (double)w.x, acc[r]);
      acc[r] = fma(a1, (double)w.y, acc[r]);
      acc[r] = fma(a2, (double)w.z, acc[r]);
      acc[r] = fma(a3, (double)w.w, acc[r]);
    }
  }
}

// Same but A contiguous in k (the raw x input, [B,T,NIN] row)
__device__ __forceinline__ void dot8_sc(const float* __restrict__ A,
                                        const float* __restrict__ W,
                                        const int wstride, const int nk,
                                        double* __restrict__ acc) {
#pragma unroll 2
  for (int k = 0; k < nk; k += 4) {
    float4 av = *(const float4*)(A + k);
#pragma unroll
    for (int r = 0; r < 8; ++r) {
      float4 w = *(const float4*)(W + r * wstride + k);
      acc[r] = fma((double)av.x, (double)w.x, acc[r]);
      acc[r] = fma((double)av.y, (double)w.y, acc[r]);
      acc[r] = fma((double)av.z, (double)w.z, acc[r]);
      acc[r] = fma((double)av.w, (double)w.w, acc[r]);
    }
  }
}

// two-plane K-group reduction: kg0/kg1 write planes, kg2/kg3 accumulate into them
__device__ __forceinline__ void reduce_partials(float* __restrict__ pb,
                                                const double* __restrict__ acc,
                                                int kg, int b) {
  if (kg < 2) {
#pragma unroll
    for (int r = 0; r < 8; ++r) pb[(kg * 8 + r) * 64 + b] = (float)acc[r];
  }
  __syncthreads();
  if (kg >= 2) {
#pragma unroll
    for (int r = 0; r < 8; ++r) pb[((kg - 2) * 8 + r) * 64 + b] += (float)acc[r];
  }
  __syncthreads();
}

__device__ __forceinline__ float lstm_cell(const float* __restrict__ pb,
                                           const double* __restrict__ bias,
                                           int r0, int b, double* c) {
  double gi = (double)pb[(r0 + 0) * 64 + b] + (double)pb[(8 + r0 + 0) * 64 + b] + bias[r0 + 0];
  double gf = (double)pb[(r0 + 1) * 64 + b] + (double)pb[(8 + r0 + 1) * 64 + b] + bias[r0 + 1];
  double gg = (double)pb[(r0 + 2) * 64 + b] + (double)pb[(8 + r0 + 2) * 64 + b] + bias[r0 + 2];
  double go = (double)pb[(r0 + 3) * 64 + b] + (double)pb[(8 + r0 + 3) * 64 + b] + bias[r0 + 3];
  double cn = dsig(gf) * (*c) + dsig(gi) * tanh(gg);
  *c = cn;
  return (float)(dsig(go) * tanh(cn));
}

extern "C" __global__ __launch_bounds__(NTHR, 1)
void lstm_seq_kernel(const float* __restrict__ x,      // [B,T,NIN]
                     const float* __restrict__ h0in,   // [L,B,H]
                     const float* __restrict__ c0in,   // [L,B,H]
                     const float* __restrict__ Wih0,   // [4H,NIN]
                     const float* __restrict__ Wih1,   // [4H,H]
                     const float* __restrict__ Whh,    // [L,4H,H]
                     const float* __restrict__ bih,    // [L,4H]
                     const float* __restrict__ bhh,    // [L,4H]
                     const float* __restrict__ Wemb,   // [NOUT,H]
                     const float* __restrict__ bemb,   // [NOUT]
                     const unsigned char* __restrict__ uprev, // [T] bool (or int32 — autodetected)
                     float* __restrict__ out,          // [B,T,NOUT]
                     float* __restrict__ ws) {
  // LDS: resident weights for this block's 2 hidden units (+1 head row)
  __shared__ __align__(16) float wl0[8 * 768];    // [r][ W_ih0(256) | W_hh0(512) ]
  __shared__ __align__(16) float wl1[8 * 1024];   // [r][ W_ih1(512) | W_hh1(512) ]
  __shared__ __align__(16) float whd[512];        // W_emb row `blk`
  __shared__ __align__(16) float pbuf[2 * 8 * 64];
  __shared__ double biasesD[2][8];
  __shared__ double bembs;
  __shared__ int up_mode;                          // 1 = int32 array, 0 = byte array

  const int tid = threadIdx.x;
  const int blk = blockIdx.x;
  const int b   = tid & 63;
  const int kg  = tid >> 6;   // wave index = K-group
  const int j0  = blk * 2;    // this block's hidden units: j0, j0+1

  unsigned* cnt = (unsigned*)ws;
  float* hbuf = ws + 64;                       // [2 parity][L][H][B]
  float* outT = hbuf + 2 * 2 * Hc * Bc;        // [NOUT][B]

  // ---- detect use_prev dtype: int32 arrays (values 0/1) have zero bytes at idx%4!=0 ----
  if (tid == 0) up_mode = 1;
  __syncthreads();
  {
    int bad = 0;
    for (int idx = tid; idx < Tc; idx += NTHR)
      if ((idx & 3) && uprev[idx]) bad = 1;
    if (bad) up_mode = 0;   // benign: all writers store 0
  }

  // ---- load weights into LDS (rows r = u*4+g; gate order i,f,g,o) ----
  for (int r = 0; r < 8; ++r) {
    const int u = r >> 2, g = r & 3;
    const int row = g * Hc + (j0 + u);
    const float* sA = Wih0 + (size_t)row * NINc;
    const float* sB = Whh  + (size_t)row * Hc;                         // layer 0 W_hh
    const float* sC = Wih1 + (size_t)row * Hc;
    const float* sD = Whh  + (size_t)(4 * Hc) * Hc + (size_t)row * Hc; // layer 1 W_hh
    for (int i = tid; i < NINc; i += NTHR) wl0[r * 768 + i] = sA[i];
    for (int i = tid; i < Hc;   i += NTHR) wl0[r * 768 + NINc + i] = sB[i];
    for (int i = tid; i < Hc;   i += NTHR) wl1[r * 1024 + i] = sC[i];
    for (int i = tid; i < Hc;   i += NTHR) wl1[r * 1024 + Hc + i] = sD[i];
    if (tid == 0) {
      biasesD[0][r] = (double)bih[row] + (double)bhh[row];
      biasesD[1][r] = (double)bih[4 * Hc + row] + (double)bhh[4 * Hc + row];
    }
  }
  for (int i = tid; i < Hc; i += NTHR) whd[i] = Wemb[(size_t)blk * Hc + i];
  if (tid == 0) bembs = (double)bemb[blk];

  // ---- init h (parity 0) transposed to [L][H][B]; exactly 1 elem per thread ----
  for (int idx = blk * NTHR + tid; idx < 2 * Hc * Bc; idx += NBLK * NTHR) {
    const int l   = idx / (Hc * Bc);
    const int rem = idx - l * (Hc * Bc);
    const int j   = rem >> 6;
    const int bb  = rem & 63;
    hbuf[idx] = h0in[((size_t)l * Bc + bb) * Hc + j];
  }

  // ---- cell state lives in registers of threads 0..127 (f64 for accuracy) ----
  double c0r = 0.0, c1r = 0.0;
  const int cu = tid >> 6;  // unit index (valid when tid<128)
  if (tid < 128) {
    const int j = j0 + cu;
    c0r = (double)c0in[((size_t)0 * Bc + b) * Hc + j];
    c1r = (double)c0in[((size_t)1 * Bc + b) * Hc + j];
  }
  __syncthreads();
  const int upm = up_mode;
  const int* uprev32 = (const int*)uprev;

  unsigned epoch = 0;
  gridbar(cnt, ++epoch * NBLK);

  for (int t = 0; t < Tc; ++t) {
    const int p = t & 1;
    const float* hRd = hbuf + p * (2 * Hc * Bc);
    float* hWr = hbuf + (p ^ 1) * (2 * Hc * Bc);
    const bool up = upm ? (uprev32[t] != 0) : (uprev[t] != 0);

    double acc[8];

    // ================= layer 0 =================
#pragma unroll
    for (int r = 0; r < 8; ++r) acc[r] = 0.0;
    if (up) {
      dot8_sb(outT + (kg * 64) * Bc + b, &wl0[kg * 64], 768, 64, acc);
    } else {
      dot8_sc(x + ((size_t)b * Tc + t) * NINc + kg * 64, &wl0[kg * 64], 768, 64, acc);
    }
    dot8_sb(hRd + (kg * 128) * Bc + b, &wl0[NINc + kg * 128], 768, 128, acc);
    reduce_partials(pbuf, acc, kg, b);
    if (tid < 128) {
      float hn = lstm_cell(pbuf, biasesD[0], cu * 4, b, &c0r);
      hWr[(j0 + cu) * Bc + b] = hn;
    }
    gridbar(cnt, ++epoch * NBLK);

    // ================= layer 1 =================
#pragma unroll
    for (int r = 0; r < 8; ++r) acc[r] = 0.0;
    dot8_sb(hWr + (kg * 128) * Bc + b,           &wl1[kg * 128],      1024, 128, acc);
    dot8_sb(hRd + Hc * Bc + (kg * 128) * Bc + b, &wl1[Hc + kg * 128], 1024, 128, acc);
    reduce_partials(pbuf, acc, kg, b);
    if (tid < 128) {
      float hn = lstm_cell(pbuf, biasesD[1], cu * 4, b, &c1r);
      hWr[Hc * Bc + (j0 + cu) * Bc + b] = hn;
    }
    gridbar(cnt, ++epoch * NBLK);

    // ================= head (row n = blk) =================
    {
      const float* Ah = hWr + Hc * Bc + (kg * 128) * Bc + b;
      const float* Wh = &whd[kg * 128];
      double h0a = 0.0, h1a = 0.0, h2a = 0.0, h3a = 0.0;
#pragma unroll 2
      for (int k = 0; k < 128; k += 4) {
        float4 w = *(const float4*)(Wh + k);
        h0a = fma((double)Ah[(k + 0) * Bc], (double)w.x, h0a);
        h1a = fma((double)Ah[(k + 1) * Bc], (double)w.y, h1a);
        h2a = fma((double)Ah[(k + 2) * Bc], (double)w.z, h2a);
        h3a = fma((double)Ah[(k + 3) * Bc], (double)w.w, h3a);
      }
      pbuf[kg * 64 + b] = (float)((h0a + h1a) + (h2a + h3a));
    }
    __syncthreads();
    if (tid < 64) {
      double s = (double)pbuf[b] + (double)pbuf[64 + b] +
                 (double)pbuf[128 + b] + (double)pbuf[192 + b] + bembs;
      float o = (float)tanh(s);
      outT[blk * Bc + b] = o;                          // feedback buffer [NOUT][B]
      out[((size_t)b * Tc + t) * NOUTc + blk] = o;     // final output [B,T,NOUT]
    }
    // barrier only needed before next step if it reads the head output back
    if (t + 1 < Tc) {
      const bool upn = upm ? (uprev32[t + 1] != 0) : (uprev[t + 1] != 0);
      if (upn) gridbar(cnt, ++epoch * NBLK);
      else __syncthreads();
    }
  }
}

extern "C" void kernel_launch(void* const* d_in, const int* in_sizes, int n_in,
                              void* d_out, int out_size, void* d_ws, size_t ws_size,
                              hipStream_t stream) {
  const float* x    = (const float*)d_in[0];
  const float* h0   = (const float*)d_in[1];
  const float* c0   = (const float*)d_in[2];
  const float* Wih0 = (const float*)d_in[3];
  const float* Wih1 = (const float*)d_in[4];
  const float* Whh  = (const float*)d_in[5];
  const float* bih  = (const float*)d_in[6];
  const float* bhh  = (const float*)d_in[7];
  const float* Wemb = (const float*)d_in[8];
  const float* bemb = (const float*)d_in[9];
  const unsigned char* uprev = (const unsigned char*)d_in[10];
  float* out = (float*)d_out;
  float* ws  = (float*)d_ws;

  // zero the barrier counter region (first 256 B of ws) every call
  hipMemsetAsync(d_ws, 0, 256, stream);

  void* args[] = {(void*)&x, (void*)&h0, (void*)&c0, (void*)&Wih0, (void*)&Wih1,
                  (void*)&Whh, (void*)&bih, (void*)&bhh, (void*)&Wemb, (void*)&bemb,
                  (void*)&uprev, (void*)&out, (void*)&ws};
  hipLaunchCooperativeKernel((void*)lstm_seq_kernel, dim3(NBLK), dim3(NTHR),
                             args, 0, stream);
}